// Round 15
// baseline (71.298 us; speedup 1.0000x reference)
//
#include <hip/hip_runtime.h>

#define B 2
#define S 2048
#define D 512
#define H 8
#define KD 64

typedef __bf16 bf16_t;
typedef __bf16 bf16x8 __attribute__((ext_vector_type(8)));
typedef __bf16 bf16x4 __attribute__((ext_vector_type(4)));
typedef float f32x4 __attribute__((ext_vector_type(4)));

#define QSCALE 0.1803368801111204f   /* 0.125 * log2(e): exp2-domain softmax */

__device__ __forceinline__ void async_copy16(const void* g, void* l) {
    __builtin_amdgcn_global_load_lds(
        (const __attribute__((address_space(1))) void*)g,
        (__attribute__((address_space(3))) void*)l, 16, 0, 0);
}

__device__ __forceinline__ float max3f(float a, float b, float c) {
    float d;
    asm("v_max3_f32 %0, %1, %2, %3" : "=v"(d) : "v"(a), "v"(b), "v"(c));
    return d;
}

// Raw 2^x (bounded inputs; big-negative -> 0 is wanted). Avoids libm guards.
#if __has_builtin(__builtin_amdgcn_exp2f)
__device__ __forceinline__ float fexp2(float x) { return __builtin_amdgcn_exp2f(x); }
#else
__device__ __forceinline__ float fexp2(float x) {
    float r;
    asm("v_exp_f32 %0, %1\n\ts_nop 1" : "=v"(r) : "v"(x));
    return r;
}
#endif

// ---------------------------------------------------------------------------
// Kernel 0: weight prep + X conversion, one launch. (verified R12)
// ---------------------------------------------------------------------------
__global__ __launch_bounds__(256) void prep_kernel(
    const float* __restrict__ Wq, const float* __restrict__ Wk,
    const float* __restrict__ Wv, const float* __restrict__ Wo,
    const float* __restrict__ qin, const float* __restrict__ kin, const float* __restrict__ vin,
    bf16_t* __restrict__ Wtq, bf16_t* __restrict__ Wtk,
    bf16_t* __restrict__ Wtv, bf16_t* __restrict__ WoT,
    bf16_t* __restrict__ xq, bf16_t* __restrict__ xk, bf16_t* __restrict__ xv)
{
    __shared__ bf16_t tl[64][72];
    const int blk = blockIdx.x, t = threadIdx.x;

    if (blk >= 256) {   // ---- xcvt part ----
        const int idx = blk - 256;
        const int mat = idx >> 10, cidx = idx & 1023;
        const float* src = (mat == 0) ? qin : (mat == 1) ? kin : vin;
        bf16_t* dst = (mat == 0) ? xq : (mat == 1) ? xk : xv;
        const size_t i8 = ((size_t)cidx * 256 + t) * 8;
        const float4 f0 = *reinterpret_cast<const float4*>(src + i8);
        const float4 f1 = *reinterpret_cast<const float4*>(src + i8 + 4);
        bf16x8 o;
        o[0] = (bf16_t)f0.x; o[1] = (bf16_t)f0.y; o[2] = (bf16_t)f0.z; o[3] = (bf16_t)f0.w;
        o[4] = (bf16_t)f1.x; o[5] = (bf16_t)f1.y; o[6] = (bf16_t)f1.z; o[7] = (bf16_t)f1.w;
        *reinterpret_cast<bf16x8*>(dst + i8) = o;
        return;
    }

    const float* src; bf16_t* dstbase;
    int ld, r0, c0;
    if (blk < 192) {
        const int mat = blk >> 6, h = (blk & 63) >> 3, dt = blk & 7;
        const float* W = (mat == 0) ? Wq : (mat == 1) ? Wk : Wv;
        bf16_t* Wt = (mat == 0) ? Wtq : (mat == 1) ? Wtk : Wtv;
        src = W + (size_t)h * D * KD; dstbase = Wt + (size_t)h * KD * D;
        ld = KD; r0 = dt * 64; c0 = 0;
    } else {
        const int kt = (blk - 192) >> 3, nt = (blk - 192) & 7;
        src = Wo; dstbase = WoT;
        ld = D; r0 = kt * 64; c0 = nt * 64;
    }

    {
        const int r = t >> 2, cq = (t & 3) * 16;
        const float* sp = src + (size_t)(r0 + r) * ld + c0 + cq;
#pragma unroll
        for (int q = 0; q < 4; ++q) {
            const float4 f = *reinterpret_cast<const float4*>(sp + q * 4);
            tl[r][cq + q * 4 + 0] = (bf16_t)f.x; tl[r][cq + q * 4 + 1] = (bf16_t)f.y;
            tl[r][cq + q * 4 + 2] = (bf16_t)f.z; tl[r][cq + q * 4 + 3] = (bf16_t)f.w;
        }
    }
    __syncthreads();
    {
        const int cc = t >> 2, rq = (t & 3) * 16;
        bf16x8 o0, o1;
#pragma unroll
        for (int j = 0; j < 8; ++j) { o0[j] = tl[rq + j][cc]; o1[j] = tl[rq + 8 + j][cc]; }
        bf16_t* dp = dstbase + (size_t)(c0 + cc) * 512 + r0 + rq;
        *reinterpret_cast<bf16x8*>(dp) = o0;
        *reinterpret_cast<bf16x8*>(dp + 8) = o1;
    }
}

// ---------------------------------------------------------------------------
// Shared 128x64-tile GEMM mainloop (verified R13/R14 in qkv):
// BK=64, dbuf global_load_lds, XOR-swizzled LDS, 4 waves x 64x32 output.
// acc[4][2]: rows row0 + (wave>>1)*64 + mf*16 + 4g+i, cols n0 + (wave&1)*32 + nf*16 + c.
// ---------------------------------------------------------------------------
__device__ __forceinline__ void gemm_tile128(
    const bf16_t* __restrict__ A, const bf16_t* __restrict__ Bt,
    int row0, int n0, char* lds0, char* lds1, f32x4 (&acc)[4][2])
{
    const int tid = threadIdx.x, wave = tid >> 6, lane = tid & 63;
    const int g = lane >> 4, c = lane & 15;
    const int srow8 = lane >> 3, sslot = lane & 7;

    const bf16_t* asrc[4]; const bf16_t* bsrc[2];
#pragma unroll
    for (int j = 0; j < 4; ++j) {
        const int r = wave * 32 + j * 8 + srow8;
        const int ys = srow8 ^ ((j & 1) << 2);
        asrc[j] = A + (size_t)(row0 + r) * 512 + ((sslot ^ ys) << 3);
    }
#pragma unroll
    for (int j = 0; j < 2; ++j) {
        const int r = wave * 16 + j * 8 + srow8;
        const int ys = srow8 ^ ((j & 1) << 2);
        bsrc[j] = Bt + (size_t)(n0 + r) * 512 + ((sslot ^ ys) << 3);
    }
    const int adst = wave * 4096;
    const int bdst = 16384 + wave * 2048;

    const int ysr = (c & 7) ^ (((c >> 3) & 1) << 2);
    const int wm = wave >> 1, wn = wave & 1;
    int ard[4], brd[2];
#pragma unroll
    for (int f = 0; f < 4; ++f) ard[f] = (wm * 64 + f * 16 + c) * 128;
#pragma unroll
    for (int f = 0; f < 2; ++f) brd[f] = 16384 + (wn * 32 + f * 16 + c) * 128;

#define QSTAGE(bp, kt)                                                         \
    do {                                                                       \
        _Pragma("unroll") for (int j = 0; j < 4; ++j)                          \
            async_copy16(asrc[j] + (kt) * 64, (bp) + adst + j * 1024);         \
        _Pragma("unroll") for (int j = 0; j < 2; ++j)                          \
            async_copy16(bsrc[j] + (kt) * 64, (bp) + bdst + j * 1024);         \
    } while (0)

    char* bufs[2] = {lds0, lds1};
    int buf = 0;
    QSTAGE(bufs[0], 0);
    __syncthreads();
#pragma unroll 1
    for (int kt = 0; kt < 8; ++kt) {
        if (kt < 7) QSTAGE(bufs[buf ^ 1], kt + 1);
        const char* bp = bufs[buf];
        __builtin_amdgcn_s_setprio(1);
#pragma unroll
        for (int ksub = 0; ksub < 2; ++ksub) {
            const int so = (((ksub << 2) | g) ^ ysr) << 4;
            const bf16x8 bfr0 = *reinterpret_cast<const bf16x8*>(bp + brd[0] + so);
            const bf16x8 bfr1 = *reinterpret_cast<const bf16x8*>(bp + brd[1] + so);
#pragma unroll
            for (int mf = 0; mf < 4; ++mf) {
                const bf16x8 afr = *reinterpret_cast<const bf16x8*>(bp + ard[mf] + so);
                acc[mf][0] = __builtin_amdgcn_mfma_f32_16x16x32_bf16(afr, bfr0, acc[mf][0], 0, 0, 0);
                acc[mf][1] = __builtin_amdgcn_mfma_f32_16x16x32_bf16(afr, bfr1, acc[mf][1], 0, 0, 0);
            }
        }
        __builtin_amdgcn_s_setprio(0);
        __syncthreads();
        buf ^= 1;
    }
#undef QSTAGE
}

// ---------------------------------------------------------------------------
// Kernel 1: fused QKV projection, 128x64 tile. grid (256, 3) x 256 thr.
// ---------------------------------------------------------------------------
__global__ __launch_bounds__(256) void qkv_kernel(
    const bf16_t* __restrict__ xq, const bf16_t* __restrict__ xk, const bf16_t* __restrict__ xv,
    const bf16_t* __restrict__ Wtq, const bf16_t* __restrict__ Wtk, const bf16_t* __restrict__ Wtv,
    const float* __restrict__ bq, const float* __restrict__ bk, const float* __restrict__ bv,
    bf16_t* __restrict__ Qo, bf16_t* __restrict__ Ko, bf16_t* __restrict__ VTo)
{
    __shared__ char lds[2][24576];   // A [128][128B] | B [64][128B] per buf

    const int mat = blockIdx.y;
    const bf16_t* A    = (mat == 0) ? xq  : (mat == 1) ? xk  : xv;
    const bf16_t* Bt   = (mat == 0) ? Wtq : (mat == 1) ? Wtk : Wtv;
    const float* bias  = (mat == 0) ? bq  : (mat == 1) ? bk  : bv;
    const float scale  = (mat == 0) ? QSCALE : 1.0f;

    const int mtile = blockIdx.x & 31;      // low bits -> XCD (A-panel sharers co-XCD)
    const int ntile = blockIdx.x >> 5;      // 0..7
    const int row0 = mtile * 128, n0 = ntile * 64;

    const int lane = threadIdx.x & 63;
    const int g = lane >> 4, c = lane & 15;
    const int wave = threadIdx.x >> 6, wm = wave >> 1, wn = wave & 1;

    const f32x4 zero = {0.f, 0.f, 0.f, 0.f};
    f32x4 acc[4][2] = {{zero, zero}, {zero, zero}, {zero, zero}, {zero, zero}};
    gemm_tile128(A, Bt, row0, n0, lds[0], lds[1], acc);

#pragma unroll
    for (int mf = 0; mf < 4; ++mf)
#pragma unroll
        for (int nf = 0; nf < 2; ++nf) {
            const int n = n0 + wn * 32 + nf * 16 + c;
            const int h = n >> 6, col = n & 63;
            const float bval = bias[n];
            const int rowb = row0 + wm * 64 + mf * 16 + 4 * g;
            const int b = rowb >> 11, s0 = rowb & 2047;
            const int bh = b * H + h;
            if (mat < 2) {
                bf16_t* outp = (mat == 0) ? Qo : Ko;
#pragma unroll
                for (int i = 0; i < 4; ++i)
                    outp[((size_t)bh * S + s0 + i) * KD + col] =
                        (bf16_t)((acc[mf][nf][i] + bval) * scale);
            } else {
                bf16x4 o;
#pragma unroll
                for (int i = 0; i < 4; ++i) o[i] = (bf16_t)(acc[mf][nf][i] + bval);
                *reinterpret_cast<bf16x4*>(VTo + ((size_t)bh * KD + col) * S + s0) = o;
            }
        }
}

// ---------------------------------------------------------------------------
// Kernel 2: flash attention, KV-split (verified R12).
// ---------------------------------------------------------------------------
template <int SPLIT>
__global__ __launch_bounds__(512) void attn_kernel(
    const bf16_t* __restrict__ Q, const bf16_t* __restrict__ Km,
    const bf16_t* __restrict__ VT,
    bf16_t* __restrict__ CTX, bf16_t* __restrict__ Opart, float* __restrict__ ML)
{
    __shared__ char kv_lds[2][16384];

    const int hw = blockIdx.x;
    const int xcd = hw & 7;
    const int idx = hw >> 3;
    const int bh = xcd * 2 + (idx >= 16 * SPLIT ? 1 : 0);
    const int r2 = idx & (16 * SPLIT - 1);
    const int chunk = r2 >> 4;
    const int stile = r2 & 15;
    const int b = bh >> 3, h = bh & (H - 1);

    const int tid = threadIdx.x, wave = tid >> 6, lane = tid & 63;
    const int g = lane >> 4, c = lane & 15;
    const int q0 = stile * 128 + wave * 16;
    const int kvbeg = chunk * (S / SPLIT);
    const int NT = (S / SPLIT) / 64;

    const bf16_t* kg = Km + (size_t)bh * S * KD;
    const bf16_t* vg = VT + (size_t)bh * KD * S;

    const bf16_t* qp = Q + ((size_t)bh * S + q0 + c) * KD;
    const bf16x8 qlo = *reinterpret_cast<const bf16x8*>(qp + g * 8);
    const bf16x8 qhi = *reinterpret_cast<const bf16x8*>(qp + 32 + g * 8);

    bf16x8 ones;
#pragma unroll
    for (int i = 0; i < 8; ++i) ones[i] = (bf16_t)1.0f;

    int koff[4][2], voff[4][2];
#pragma unroll
    for (int tt = 0; tt < 4; ++tt) {
        const int row = 8 * (c >> 2) + (c & 3) + 4 * (tt & 1) + 32 * (tt >> 1);
        const int ys = (row & 7) ^ (((row >> 3) & 1) << 2);
        koff[tt][0] = row * 128 + ((g * 16) ^ (ys << 4));
        koff[tt][1] = row * 128 + ((64 + g * 16) ^ (ys << 4));
    }
#pragma unroll
    for (int ct = 0; ct < 4; ++ct) {
        const int row = ct * 16 + c;
        const int ys = (row & 7) ^ (((row >> 3) & 1) << 2);
        voff[ct][0] = 8192 + row * 128 + ((g * 16) ^ (ys << 4));
        voff[ct][1] = 8192 + row * 128 + ((64 + g * 16) ^ (ys << 4));
    }

    const int srow = lane >> 3, sslot = lane & 7;
    const int kwv = wave & 3;
    const int krow0a = kwv * 16, krow0b = kwv * 16 + 8;
    const int rowa = krow0a + srow, rowb = krow0b + srow;
    const int ysa = (rowa & 7) ^ (((rowa >> 3) & 1) << 2);
    const int ysb = (rowb & 7) ^ (((rowb >> 3) & 1) << 2);
    const int ssa = sslot ^ ysa, ssb = sslot ^ ysb;

    const f32x4 zero = {0.f, 0.f, 0.f, 0.f};
    f32x4 acc[4] = {zero, zero, zero, zero};
    f32x4 accl = zero;
    float m_run = -1e30f;

#define STAGE(bufidx, kv0)                                                        \
    do {                                                                          \
        char* bp = kv_lds[0] + (bufidx) * 16384;                                  \
        if (wave < 4) {                                                           \
            async_copy16(kg + (size_t)((kv0) + rowa) * KD + ssa * 8, bp + krow0a * 128); \
            async_copy16(kg + (size_t)((kv0) + rowb) * KD + ssb * 8, bp + krow0b * 128); \
        } else {                                                                  \
            async_copy16(vg + (size_t)rowa * S + (kv0) + ssa * 8, bp + 8192 + krow0a * 128); \
            async_copy16(vg + (size_t)rowb * S + (kv0) + ssb * 8, bp + 8192 + krow0b * 128); \
        }                                                                         \
    } while (0)

    STAGE(0, kvbeg);
    __syncthreads();

    int buf = 0;
    for (int t = 0; t < NT; ++t) {
        if (t < NT - 1) STAGE(buf ^ 1, kvbeg + (t + 1) * 64);
        const char* kb = kv_lds[0] + buf * 16384;

        f32x4 sc[4];
        __builtin_amdgcn_s_setprio(1);
#pragma unroll
        for (int tt = 0; tt < 4; ++tt) {
            const bf16x8 k0f = *reinterpret_cast<const bf16x8*>(kb + koff[tt][0]);
            const bf16x8 k1f = *reinterpret_cast<const bf16x8*>(kb + koff[tt][1]);
            f32x4 z = zero;
            z = __builtin_amdgcn_mfma_f32_16x16x32_bf16(k0f, qlo, z, 0, 0, 0);
            sc[tt] = __builtin_amdgcn_mfma_f32_16x16x32_bf16(k1f, qhi, z, 0, 0, 0);
        }
        __builtin_amdgcn_s_setprio(0);

        const float m0 = max3f(sc[0][0], sc[0][1], sc[0][2]);
        const float m1 = max3f(sc[0][3], sc[1][0], sc[1][1]);
        const float m2 = max3f(sc[1][2], sc[1][3], sc[2][0]);
        const float m3 = max3f(sc[2][1], sc[2][2], sc[2][3]);
        const float m4 = max3f(sc[3][0], sc[3][1], sc[3][2]);
        float pm = fmaxf(max3f(max3f(m0, m1, m2), m3, m4), sc[3][3]);
        if (!__all(pm <= m_run + 8.0f)) {
            pm = fmaxf(pm, __shfl_xor(pm, 16));
            pm = fmaxf(pm, __shfl_xor(pm, 32));
            const float mn = fmaxf(m_run, pm);
            const float fs = fexp2(m_run - mn);
            m_run = mn;
            accl = accl * fs;
#pragma unroll
            for (int ct = 0; ct < 4; ++ct) acc[ct] = acc[ct] * fs;
        }

        bf16x8 f0, f1;
#pragma unroll
        for (int i = 0; i < 4; ++i) {
            f0[i]     = (bf16_t)fexp2(sc[0][i] - m_run);
            f0[4 + i] = (bf16_t)fexp2(sc[1][i] - m_run);
            f1[i]     = (bf16_t)fexp2(sc[2][i] - m_run);
            f1[4 + i] = (bf16_t)fexp2(sc[3][i] - m_run);
        }

        __builtin_amdgcn_s_setprio(1);
        accl = __builtin_amdgcn_mfma_f32_16x16x32_bf16(ones, f0, accl, 0, 0, 0);
        accl = __builtin_amdgcn_mfma_f32_16x16x32_bf16(ones, f1, accl, 0, 0, 0);
#pragma unroll
        for (int ct = 0; ct < 4; ++ct) {
            const bf16x8 v0f = *reinterpret_cast<const bf16x8*>(kb + voff[ct][0]);
            const bf16x8 v1f = *reinterpret_cast<const bf16x8*>(kb + voff[ct][1]);
            acc[ct] = __builtin_amdgcn_mfma_f32_16x16x32_bf16(v0f, f0, acc[ct], 0, 0, 0);
            acc[ct] = __builtin_amdgcn_mfma_f32_16x16x32_bf16(v1f, f1, acc[ct], 0, 0, 0);
        }
        __builtin_amdgcn_s_setprio(0);

        __syncthreads();
        buf ^= 1;
    }
#undef STAGE

    const float l_tot = accl[0];

    if constexpr (SPLIT == 1) {
        const float inv = 1.0f / l_tot;
        bf16_t* crow = CTX + ((size_t)b * S + q0 + c) * 512 + h * 64;
#pragma unroll
        for (int ct = 0; ct < 4; ++ct) {
            bf16x4 o;
#pragma unroll
            for (int i = 0; i < 4; ++i) o[i] = (bf16_t)(acc[ct][i] * inv);
            *reinterpret_cast<bf16x4*>(crow + ct * 16 + 4 * g) = o;
        }
    } else {
        const size_t prow = (size_t)(chunk * 16 + bh) * 2048 + q0 + c;
        bf16_t* orow = Opart + prow * 64;
#pragma unroll
        for (int ct = 0; ct < 4; ++ct) {
            bf16x4 o;
#pragma unroll
            for (int i = 0; i < 4; ++i) o[i] = (bf16_t)acc[ct][i];
            *reinterpret_cast<bf16x4*>(orow + ct * 16 + 4 * g) = o;
        }
        if (g == 0) {
            float2 ml; ml.x = m_run; ml.y = l_tot;
            *reinterpret_cast<float2*>(ML + prow * 2) = ml;
        }
    }
}

// ---------------------------------------------------------------------------
// Kernel 2b: combine KV-split partials (bf16 O, f32 m/l) -> bf16 ctx. (R12)
// ---------------------------------------------------------------------------
template <int SPLIT>
__global__ __launch_bounds__(256) void combine_kernel(
    const bf16_t* __restrict__ Opart, const float* __restrict__ ML,
    bf16_t* __restrict__ CTX)
{
    const int gid = blockIdx.x * 256 + threadIdx.x;
    const int d4 = gid & 15, rowh = gid >> 4;
    const int bh = rowh >> 11, s = rowh & 2047;
    const int b = bh >> 3, h = bh & (H - 1);

    float m[SPLIT], l[SPLIT], M = -1e30f;
#pragma unroll
    for (int i = 0; i < SPLIT; ++i) {
        const float2 v = *reinterpret_cast<const float2*>(
            ML + ((size_t)(i * 16 + bh) * 2048 + s) * 2);
        m[i] = v.x; l[i] = v.y;
        M = fmaxf(M, m[i]);
    }
    f32x4 o = {0.f, 0.f, 0.f, 0.f};
    float wsum = 0.f;
#pragma unroll
    for (int i = 0; i < SPLIT; ++i) {
        const float w = fexp2(m[i] - M);
        wsum += w * l[i];
        const bf16x4 ov = *reinterpret_cast<const bf16x4*>(
            Opart + ((size_t)(i * 16 + bh) * 2048 + s) * 64 + d4 * 4);
#pragma unroll
        for (int j = 0; j < 4; ++j) o[j] += w * (float)ov[j];
    }
    const float inv = 1.0f / wsum;
    bf16x4 r;
#pragma unroll
    for (int i = 0; i < 4; ++i) r[i] = (bf16_t)(o[i] * inv);
    *reinterpret_cast<bf16x4*>(CTX + ((size_t)b * S + s) * 512 + h * 64 + d4 * 4) = r;
}

// ---------------------------------------------------------------------------
// Kernel 3: output projection, 128x64 tile (same proven mainloop as qkv).
// grid 256 x 256 thr (32 mtiles x 8 ntiles).
// ---------------------------------------------------------------------------
__global__ __launch_bounds__(256) void out_proj_kernel(
    const bf16_t* __restrict__ CTX,
    const bf16_t* __restrict__ WoT,
    const float* __restrict__ bo,
    float* __restrict__ out)
{
    __shared__ char lds[2][24576];

    const int mtile = blockIdx.x & 31;      // low bits -> XCD
    const int ntile = blockIdx.x >> 5;
    const int row0 = mtile * 128, n0 = ntile * 64;

    const int lane = threadIdx.x & 63;
    const int g = lane >> 4, c = lane & 15;
    const int wave = threadIdx.x >> 6, wm = wave >> 1, wn = wave & 1;

    const f32x4 zero = {0.f, 0.f, 0.f, 0.f};
    f32x4 acc[4][2] = {{zero, zero}, {zero, zero}, {zero, zero}, {zero, zero}};
    gemm_tile128(CTX, WoT, row0, n0, lds[0], lds[1], acc);

#pragma unroll
    for (int mf = 0; mf < 4; ++mf)
#pragma unroll
        for (int nf = 0; nf < 2; ++nf) {
            const int n = n0 + wn * 32 + nf * 16 + c;
            const float bval = bo[n];
            const int rowb = row0 + wm * 64 + mf * 16 + 4 * g;
#pragma unroll
            for (int i = 0; i < 4; ++i)
                out[(size_t)(rowb + i) * 512 + n] = acc[mf][nf][i] + bval;
        }
}

// ---------------------------------------------------------------------------
extern "C" void kernel_launch(void* const* d_in, const int* in_sizes, int n_in,
                              void* d_out, int out_size, void* d_ws, size_t ws_size,
                              hipStream_t stream) {
    const float* query = (const float*)d_in[0];
    const float* key_  = (const float*)d_in[1];
    const float* value = (const float*)d_in[2];
    const float* Wq = (const float*)d_in[3];
    const float* bq = (const float*)d_in[4];
    const float* Wk = (const float*)d_in[5];
    const float* bk = (const float*)d_in[6];
    const float* Wv = (const float*)d_in[7];
    const float* bv = (const float*)d_in[8];
    const float* Wo = (const float*)d_in[9];
    const float* bo = (const float*)d_in[10];

    char* wsb = (char*)d_ws;
    bf16_t* Qw   = (bf16_t*)(wsb);                       // 4 MB
    bf16_t* Kw   = (bf16_t*)(wsb + (4u  << 20));         // 4 MB
    bf16_t* VTw  = (bf16_t*)(wsb + (8u  << 20));         // 4 MB
    bf16_t* CTXb = (bf16_t*)(wsb + (12u << 20));         // 4 MB
    bf16_t* Wtq  = (bf16_t*)(wsb + (16u << 20));         // 512 KB
    bf16_t* Wtk  = Wtq + 8 * 64 * 512;
    bf16_t* Wtv  = Wtk + 8 * 64 * 512;
    bf16_t* WoTw = (bf16_t*)(wsb + (18u << 20));         // 512 KB
    bf16_t* Xq   = (bf16_t*)(wsb + (20u << 20));         // 4 MB
    bf16_t* Xk   = (bf16_t*)(wsb + (24u << 20));         // 4 MB
    bf16_t* Xv   = (bf16_t*)(wsb + (28u << 20));         // 4 MB
    bf16_t* Opart = (bf16_t*)(wsb + (32u << 20));        // SPLIT x 4 MB (bf16)

    const int SPLIT = (ws_size >= (70ull << 20)) ? 4
                    : (ws_size >= (52ull << 20)) ? 2 : 1;

    prep_kernel<<<256 + 3072, 256, 0, stream>>>(Wq, Wk, Wv, Wo,
                                                query, key_, value,
                                                Wtq, Wtk, Wtv, WoTw,
                                                Xq, Xk, Xv);
    qkv_kernel<<<dim3(256, 3), 256, 0, stream>>>(Xq, Xk, Xv,
                                                 Wtq, Wtk, Wtv, bq, bk, bv,
                                                 Qw, Kw, VTw);

    if (SPLIT == 4) {
        float* MLp = (float*)(Opart + 4ull * 16 * 2048 * 64);
        attn_kernel<4><<<1024, 512, 0, stream>>>(Qw, Kw, VTw, CTXb, Opart, MLp);
        combine_kernel<4><<<2048, 256, 0, stream>>>(Opart, MLp, CTXb);
    } else if (SPLIT == 2) {
        float* MLp = (float*)(Opart + 2ull * 16 * 2048 * 64);
        attn_kernel<2><<<512, 512, 0, stream>>>(Qw, Kw, VTw, CTXb, Opart, MLp);
        combine_kernel<2><<<2048, 256, 0, stream>>>(Opart, MLp, CTXb);
    } else {
        attn_kernel<1><<<256, 512, 0, stream>>>(Qw, Kw, VTw, CTXb, nullptr, nullptr);
    }

    out_proj_kernel<<<256, 256, 0, stream>>>(CTXb, WoTw, bo, (float*)d_out);
}

// Round 16
// 64.298 us; speedup vs baseline: 1.1089x; 1.1089x over previous
//
#include <hip/hip_runtime.h>

#define B 2
#define S 2048
#define D 512
#define H 8
#define KD 64

typedef __bf16 bf16_t;
typedef __bf16 bf16x8 __attribute__((ext_vector_type(8)));
typedef __bf16 bf16x4 __attribute__((ext_vector_type(4)));
typedef float f32x4 __attribute__((ext_vector_type(4)));

#define QSCALE 0.1803368801111204f   /* 0.125 * log2(e): exp2-domain softmax */

__device__ __forceinline__ void async_copy16(const void* g, void* l) {
    __builtin_amdgcn_global_load_lds(
        (const __attribute__((address_space(1))) void*)g,
        (__attribute__((address_space(3))) void*)l, 16, 0, 0);
}

__device__ __forceinline__ float max3f(float a, float b, float c) {
    float d;
    asm("v_max3_f32 %0, %1, %2, %3" : "=v"(d) : "v"(a), "v"(b), "v"(c));
    return d;
}

// Raw 2^x (bounded inputs; big-negative -> 0 is wanted). Avoids libm guards.
#if __has_builtin(__builtin_amdgcn_exp2f)
__device__ __forceinline__ float fexp2(float x) { return __builtin_amdgcn_exp2f(x); }
#else
__device__ __forceinline__ float fexp2(float x) {
    float r;
    asm("v_exp_f32 %0, %1\n\ts_nop 1" : "=v"(r) : "v"(x));
    return r;
}
#endif

// ---------------------------------------------------------------------------
// Kernel 0: weight prep + X conversion, one launch. (verified R12)
// ---------------------------------------------------------------------------
__global__ __launch_bounds__(256) void prep_kernel(
    const float* __restrict__ Wq, const float* __restrict__ Wk,
    const float* __restrict__ Wv, const float* __restrict__ Wo,
    const float* __restrict__ qin, const float* __restrict__ kin, const float* __restrict__ vin,
    bf16_t* __restrict__ Wtq, bf16_t* __restrict__ Wtk,
    bf16_t* __restrict__ Wtv, bf16_t* __restrict__ WoT,
    bf16_t* __restrict__ xq, bf16_t* __restrict__ xk, bf16_t* __restrict__ xv)
{
    __shared__ bf16_t tl[64][72];
    const int blk = blockIdx.x, t = threadIdx.x;

    if (blk >= 256) {   // ---- xcvt part ----
        const int idx = blk - 256;
        const int mat = idx >> 10, cidx = idx & 1023;
        const float* src = (mat == 0) ? qin : (mat == 1) ? kin : vin;
        bf16_t* dst = (mat == 0) ? xq : (mat == 1) ? xk : xv;
        const size_t i8 = ((size_t)cidx * 256 + t) * 8;
        const float4 f0 = *reinterpret_cast<const float4*>(src + i8);
        const float4 f1 = *reinterpret_cast<const float4*>(src + i8 + 4);
        bf16x8 o;
        o[0] = (bf16_t)f0.x; o[1] = (bf16_t)f0.y; o[2] = (bf16_t)f0.z; o[3] = (bf16_t)f0.w;
        o[4] = (bf16_t)f1.x; o[5] = (bf16_t)f1.y; o[6] = (bf16_t)f1.z; o[7] = (bf16_t)f1.w;
        *reinterpret_cast<bf16x8*>(dst + i8) = o;
        return;
    }

    const float* src; bf16_t* dstbase;
    int ld, r0, c0;
    if (blk < 192) {
        const int mat = blk >> 6, h = (blk & 63) >> 3, dt = blk & 7;
        const float* W = (mat == 0) ? Wq : (mat == 1) ? Wk : Wv;
        bf16_t* Wt = (mat == 0) ? Wtq : (mat == 1) ? Wtk : Wtv;
        src = W + (size_t)h * D * KD; dstbase = Wt + (size_t)h * KD * D;
        ld = KD; r0 = dt * 64; c0 = 0;
    } else {
        const int kt = (blk - 192) >> 3, nt = (blk - 192) & 7;
        src = Wo; dstbase = WoT;
        ld = D; r0 = kt * 64; c0 = nt * 64;
    }

    {
        const int r = t >> 2, cq = (t & 3) * 16;
        const float* sp = src + (size_t)(r0 + r) * ld + c0 + cq;
#pragma unroll
        for (int q = 0; q < 4; ++q) {
            const float4 f = *reinterpret_cast<const float4*>(sp + q * 4);
            tl[r][cq + q * 4 + 0] = (bf16_t)f.x; tl[r][cq + q * 4 + 1] = (bf16_t)f.y;
            tl[r][cq + q * 4 + 2] = (bf16_t)f.z; tl[r][cq + q * 4 + 3] = (bf16_t)f.w;
        }
    }
    __syncthreads();
    {
        const int cc = t >> 2, rq = (t & 3) * 16;
        bf16x8 o0, o1;
#pragma unroll
        for (int j = 0; j < 8; ++j) { o0[j] = tl[rq + j][cc]; o1[j] = tl[rq + 8 + j][cc]; }
        bf16_t* dp = dstbase + (size_t)(c0 + cc) * 512 + r0 + rq;
        *reinterpret_cast<bf16x8*>(dp) = o0;
        *reinterpret_cast<bf16x8*>(dp + 8) = o1;
    }
}

// ---------------------------------------------------------------------------
// Shared 64x64 GEMM mainloop (verified R9) — used by out_proj (512 blocks =
// 2 blocks/CU; the 128-tile variant at 256 blocks = 1 block/CU regressed).
// ---------------------------------------------------------------------------
__device__ __forceinline__ void gemm_tile(
    const bf16_t* __restrict__ A, const bf16_t* __restrict__ Bt,
    int row0, int n0, char* lds, f32x4 (&acc)[2][2])
{
    const int tid = threadIdx.x, wave = tid >> 6, lane = tid & 63;
    const int g = lane >> 4, c = lane & 15;

    const int srow8 = lane >> 3, sslot = lane & 7;
    const bf16_t* asrc[2]; const bf16_t* bsrc[2];
#pragma unroll
    for (int j = 0; j < 2; ++j) {
        const int r = wave * 16 + j * 8 + srow8;
        const int ys = (r & 7) ^ (((r >> 3) & 1) << 2);
        asrc[j] = A + (size_t)(row0 + r) * 512 + ((sslot ^ ys) << 3);
        bsrc[j] = Bt + (size_t)(n0 + r) * 512 + ((sslot ^ ys) << 3);
    }
    const int adst = wave * 2048;
    const int bdst = 8192 + wave * 2048;

    const int ysr = (c & 7) ^ (((c >> 3) & 1) << 2);
    const int wm = wave >> 1, wn = wave & 1;
    int ard[2], brd[2];
#pragma unroll
    for (int f = 0; f < 2; ++f) {
        ard[f] = (wm * 32 + f * 16 + c) * 128;
        brd[f] = 8192 + (wn * 32 + f * 16 + c) * 128;
    }

#define GSTAGE(bufi, kt)                                                       \
    do { char* bp = lds + (bufi) * 16384;                                      \
        _Pragma("unroll") for (int j = 0; j < 2; ++j) {                        \
            async_copy16(asrc[j] + (kt) * 64, bp + adst + j * 1024);           \
            async_copy16(bsrc[j] + (kt) * 64, bp + bdst + j * 1024);           \
        }                                                                      \
    } while (0)

    int buf = 0;
    GSTAGE(0, 0);
    __syncthreads();
#pragma unroll 1
    for (int kt = 0; kt < 8; ++kt) {
        if (kt < 7) GSTAGE(buf ^ 1, kt + 1);
        const char* bp = lds + buf * 16384;
        __builtin_amdgcn_s_setprio(1);
#pragma unroll
        for (int ksub = 0; ksub < 2; ++ksub) {
            const int so = (((ksub << 2) | g) ^ ysr) << 4;
            bf16x8 bfr[2];
#pragma unroll
            for (int nf = 0; nf < 2; ++nf)
                bfr[nf] = *reinterpret_cast<const bf16x8*>(bp + brd[nf] + so);
#pragma unroll
            for (int mf = 0; mf < 2; ++mf) {
                const bf16x8 afr = *reinterpret_cast<const bf16x8*>(bp + ard[mf] + so);
                acc[mf][0] = __builtin_amdgcn_mfma_f32_16x16x32_bf16(afr, bfr[0], acc[mf][0], 0, 0, 0);
                acc[mf][1] = __builtin_amdgcn_mfma_f32_16x16x32_bf16(afr, bfr[1], acc[mf][1], 0, 0, 0);
            }
        }
        __builtin_amdgcn_s_setprio(0);
        __syncthreads();
        buf ^= 1;
    }
#undef GSTAGE
}

// ---------------------------------------------------------------------------
// Kernel 1: fused QKV projection, 128x64 tile (verified R14).
// grid (256, 3) x 256 thr = 768 blocks = 3 blocks/CU at 48 KB LDS.
// ---------------------------------------------------------------------------
__global__ __launch_bounds__(256) void qkv_kernel(
    const bf16_t* __restrict__ xq, const bf16_t* __restrict__ xk, const bf16_t* __restrict__ xv,
    const bf16_t* __restrict__ Wtq, const bf16_t* __restrict__ Wtk, const bf16_t* __restrict__ Wtv,
    const float* __restrict__ bq, const float* __restrict__ bk, const float* __restrict__ bv,
    bf16_t* __restrict__ Qo, bf16_t* __restrict__ Ko, bf16_t* __restrict__ VTo)
{
    __shared__ char lds[2][24576];   // A [128][128B] | B [64][128B] per buf

    const int mat = blockIdx.y;
    const bf16_t* A    = (mat == 0) ? xq  : (mat == 1) ? xk  : xv;
    const bf16_t* Bt   = (mat == 0) ? Wtq : (mat == 1) ? Wtk : Wtv;
    const float* bias  = (mat == 0) ? bq  : (mat == 1) ? bk  : bv;
    const float scale  = (mat == 0) ? QSCALE : 1.0f;

    const int mtile = blockIdx.x & 31;      // low bits -> XCD (A-panel sharers co-XCD)
    const int ntile = blockIdx.x >> 5;      // 0..7
    const int row0 = mtile * 128, n0 = ntile * 64;

    const int tid = threadIdx.x, wave = tid >> 6, lane = tid & 63;
    const int g = lane >> 4, c = lane & 15;
    const int srow8 = lane >> 3, sslot = lane & 7;

    const bf16_t* asrc[4]; const bf16_t* bsrc[2];
#pragma unroll
    for (int j = 0; j < 4; ++j) {
        const int r = wave * 32 + j * 8 + srow8;
        const int ys = srow8 ^ ((j & 1) << 2);
        asrc[j] = A + (size_t)(row0 + r) * 512 + ((sslot ^ ys) << 3);
    }
#pragma unroll
    for (int j = 0; j < 2; ++j) {
        const int r = wave * 16 + j * 8 + srow8;
        const int ys = srow8 ^ ((j & 1) << 2);
        bsrc[j] = Bt + (size_t)(n0 + r) * 512 + ((sslot ^ ys) << 3);
    }
    const int adst = wave * 4096;
    const int bdst = 16384 + wave * 2048;

    const int ysr = (c & 7) ^ (((c >> 3) & 1) << 2);
    const int wm = wave >> 1, wn = wave & 1;
    int ard[4], brd[2];
#pragma unroll
    for (int f = 0; f < 4; ++f) ard[f] = (wm * 64 + f * 16 + c) * 128;
#pragma unroll
    for (int f = 0; f < 2; ++f) brd[f] = 16384 + (wn * 32 + f * 16 + c) * 128;

    const f32x4 zero = {0.f, 0.f, 0.f, 0.f};
    f32x4 acc[4][2] = {{zero, zero}, {zero, zero}, {zero, zero}, {zero, zero}};

#define QSTAGE(bufi, kt)                                                       \
    do { char* bp = lds[bufi];                                                 \
        _Pragma("unroll") for (int j = 0; j < 4; ++j)                          \
            async_copy16(asrc[j] + (kt) * 64, bp + adst + j * 1024);           \
        _Pragma("unroll") for (int j = 0; j < 2; ++j)                          \
            async_copy16(bsrc[j] + (kt) * 64, bp + bdst + j * 1024);           \
    } while (0)

    int buf = 0;
    QSTAGE(0, 0);
    __syncthreads();
#pragma unroll 1
    for (int kt = 0; kt < 8; ++kt) {
        if (kt < 7) QSTAGE(buf ^ 1, kt + 1);
        const char* bp = lds[buf];
        __builtin_amdgcn_s_setprio(1);
#pragma unroll
        for (int ksub = 0; ksub < 2; ++ksub) {
            const int so = (((ksub << 2) | g) ^ ysr) << 4;
            const bf16x8 bfr0 = *reinterpret_cast<const bf16x8*>(bp + brd[0] + so);
            const bf16x8 bfr1 = *reinterpret_cast<const bf16x8*>(bp + brd[1] + so);
#pragma unroll
            for (int mf = 0; mf < 4; ++mf) {
                const bf16x8 afr = *reinterpret_cast<const bf16x8*>(bp + ard[mf] + so);
                acc[mf][0] = __builtin_amdgcn_mfma_f32_16x16x32_bf16(afr, bfr0, acc[mf][0], 0, 0, 0);
                acc[mf][1] = __builtin_amdgcn_mfma_f32_16x16x32_bf16(afr, bfr1, acc[mf][1], 0, 0, 0);
            }
        }
        __builtin_amdgcn_s_setprio(0);
        __syncthreads();
        buf ^= 1;
    }
#undef QSTAGE

#pragma unroll
    for (int mf = 0; mf < 4; ++mf)
#pragma unroll
        for (int nf = 0; nf < 2; ++nf) {
            const int n = n0 + wn * 32 + nf * 16 + c;
            const int h = n >> 6, col = n & 63;
            const float bval = bias[n];
            const int rowb = row0 + wm * 64 + mf * 16 + 4 * g;
            const int b = rowb >> 11, s0 = rowb & 2047;
            const int bh = b * H + h;
            if (mat < 2) {
                bf16_t* outp = (mat == 0) ? Qo : Ko;
#pragma unroll
                for (int i = 0; i < 4; ++i)
                    outp[((size_t)bh * S + s0 + i) * KD + col] =
                        (bf16_t)((acc[mf][nf][i] + bval) * scale);
            } else {
                bf16x4 o;
#pragma unroll
                for (int i = 0; i < 4; ++i) o[i] = (bf16_t)(acc[mf][nf][i] + bval);
                *reinterpret_cast<bf16x4*>(VTo + ((size_t)bh * KD + col) * S + s0) = o;
            }
        }
}

// ---------------------------------------------------------------------------
// Kernel 2: flash attention, KV-split (verified R12).
// ---------------------------------------------------------------------------
template <int SPLIT>
__global__ __launch_bounds__(512) void attn_kernel(
    const bf16_t* __restrict__ Q, const bf16_t* __restrict__ Km,
    const bf16_t* __restrict__ VT,
    bf16_t* __restrict__ CTX, bf16_t* __restrict__ Opart, float* __restrict__ ML)
{
    __shared__ char kv_lds[2][16384];

    const int hw = blockIdx.x;
    const int xcd = hw & 7;
    const int idx = hw >> 3;
    const int bh = xcd * 2 + (idx >= 16 * SPLIT ? 1 : 0);
    const int r2 = idx & (16 * SPLIT - 1);
    const int chunk = r2 >> 4;
    const int stile = r2 & 15;
    const int b = bh >> 3, h = bh & (H - 1);

    const int tid = threadIdx.x, wave = tid >> 6, lane = tid & 63;
    const int g = lane >> 4, c = lane & 15;
    const int q0 = stile * 128 + wave * 16;
    const int kvbeg = chunk * (S / SPLIT);
    const int NT = (S / SPLIT) / 64;

    const bf16_t* kg = Km + (size_t)bh * S * KD;
    const bf16_t* vg = VT + (size_t)bh * KD * S;

    const bf16_t* qp = Q + ((size_t)bh * S + q0 + c) * KD;
    const bf16x8 qlo = *reinterpret_cast<const bf16x8*>(qp + g * 8);
    const bf16x8 qhi = *reinterpret_cast<const bf16x8*>(qp + 32 + g * 8);

    bf16x8 ones;
#pragma unroll
    for (int i = 0; i < 8; ++i) ones[i] = (bf16_t)1.0f;

    int koff[4][2], voff[4][2];
#pragma unroll
    for (int tt = 0; tt < 4; ++tt) {
        const int row = 8 * (c >> 2) + (c & 3) + 4 * (tt & 1) + 32 * (tt >> 1);
        const int ys = (row & 7) ^ (((row >> 3) & 1) << 2);
        koff[tt][0] = row * 128 + ((g * 16) ^ (ys << 4));
        koff[tt][1] = row * 128 + ((64 + g * 16) ^ (ys << 4));
    }
#pragma unroll
    for (int ct = 0; ct < 4; ++ct) {
        const int row = ct * 16 + c;
        const int ys = (row & 7) ^ (((row >> 3) & 1) << 2);
        voff[ct][0] = 8192 + row * 128 + ((g * 16) ^ (ys << 4));
        voff[ct][1] = 8192 + row * 128 + ((64 + g * 16) ^ (ys << 4));
    }

    const int srow = lane >> 3, sslot = lane & 7;
    const int kwv = wave & 3;
    const int krow0a = kwv * 16, krow0b = kwv * 16 + 8;
    const int rowa = krow0a + srow, rowb = krow0b + srow;
    const int ysa = (rowa & 7) ^ (((rowa >> 3) & 1) << 2);
    const int ysb = (rowb & 7) ^ (((rowb >> 3) & 1) << 2);
    const int ssa = sslot ^ ysa, ssb = sslot ^ ysb;

    const f32x4 zero = {0.f, 0.f, 0.f, 0.f};
    f32x4 acc[4] = {zero, zero, zero, zero};
    f32x4 accl = zero;
    float m_run = -1e30f;

#define STAGE(bufidx, kv0)                                                        \
    do {                                                                          \
        char* bp = kv_lds[0] + (bufidx) * 16384;                                  \
        if (wave < 4) {                                                           \
            async_copy16(kg + (size_t)((kv0) + rowa) * KD + ssa * 8, bp + krow0a * 128); \
            async_copy16(kg + (size_t)((kv0) + rowb) * KD + ssb * 8, bp + krow0b * 128); \
        } else {                                                                  \
            async_copy16(vg + (size_t)rowa * S + (kv0) + ssa * 8, bp + 8192 + krow0a * 128); \
            async_copy16(vg + (size_t)rowb * S + (kv0) + ssb * 8, bp + 8192 + krow0b * 128); \
        }                                                                         \
    } while (0)

    STAGE(0, kvbeg);
    __syncthreads();

    int buf = 0;
    for (int t = 0; t < NT; ++t) {
        if (t < NT - 1) STAGE(buf ^ 1, kvbeg + (t + 1) * 64);
        const char* kb = kv_lds[0] + buf * 16384;

        f32x4 sc[4];
        __builtin_amdgcn_s_setprio(1);
#pragma unroll
        for (int tt = 0; tt < 4; ++tt) {
            const bf16x8 k0f = *reinterpret_cast<const bf16x8*>(kb + koff[tt][0]);
            const bf16x8 k1f = *reinterpret_cast<const bf16x8*>(kb + koff[tt][1]);
            f32x4 z = zero;
            z = __builtin_amdgcn_mfma_f32_16x16x32_bf16(k0f, qlo, z, 0, 0, 0);
            sc[tt] = __builtin_amdgcn_mfma_f32_16x16x32_bf16(k1f, qhi, z, 0, 0, 0);
        }
        __builtin_amdgcn_s_setprio(0);

        const float m0 = max3f(sc[0][0], sc[0][1], sc[0][2]);
        const float m1 = max3f(sc[0][3], sc[1][0], sc[1][1]);
        const float m2 = max3f(sc[1][2], sc[1][3], sc[2][0]);
        const float m3 = max3f(sc[2][1], sc[2][2], sc[2][3]);
        const float m4 = max3f(sc[3][0], sc[3][1], sc[3][2]);
        float pm = fmaxf(max3f(max3f(m0, m1, m2), m3, m4), sc[3][3]);
        if (!__all(pm <= m_run + 8.0f)) {
            pm = fmaxf(pm, __shfl_xor(pm, 16));
            pm = fmaxf(pm, __shfl_xor(pm, 32));
            const float mn = fmaxf(m_run, pm);
            const float fs = fexp2(m_run - mn);
            m_run = mn;
            accl = accl * fs;
#pragma unroll
            for (int ct = 0; ct < 4; ++ct) acc[ct] = acc[ct] * fs;
        }

        bf16x8 f0, f1;
#pragma unroll
        for (int i = 0; i < 4; ++i) {
            f0[i]     = (bf16_t)fexp2(sc[0][i] - m_run);
            f0[4 + i] = (bf16_t)fexp2(sc[1][i] - m_run);
            f1[i]     = (bf16_t)fexp2(sc[2][i] - m_run);
            f1[4 + i] = (bf16_t)fexp2(sc[3][i] - m_run);
        }

        __builtin_amdgcn_s_setprio(1);
        accl = __builtin_amdgcn_mfma_f32_16x16x32_bf16(ones, f0, accl, 0, 0, 0);
        accl = __builtin_amdgcn_mfma_f32_16x16x32_bf16(ones, f1, accl, 0, 0, 0);
#pragma unroll
        for (int ct = 0; ct < 4; ++ct) {
            const bf16x8 v0f = *reinterpret_cast<const bf16x8*>(kb + voff[ct][0]);
            const bf16x8 v1f = *reinterpret_cast<const bf16x8*>(kb + voff[ct][1]);
            acc[ct] = __builtin_amdgcn_mfma_f32_16x16x32_bf16(v0f, f0, acc[ct], 0, 0, 0);
            acc[ct] = __builtin_amdgcn_mfma_f32_16x16x32_bf16(v1f, f1, acc[ct], 0, 0, 0);
        }
        __builtin_amdgcn_s_setprio(0);

        __syncthreads();
        buf ^= 1;
    }
#undef STAGE

    const float l_tot = accl[0];

    if constexpr (SPLIT == 1) {
        const float inv = 1.0f / l_tot;
        bf16_t* crow = CTX + ((size_t)b * S + q0 + c) * 512 + h * 64;
#pragma unroll
        for (int ct = 0; ct < 4; ++ct) {
            bf16x4 o;
#pragma unroll
            for (int i = 0; i < 4; ++i) o[i] = (bf16_t)(acc[ct][i] * inv);
            *reinterpret_cast<bf16x4*>(crow + ct * 16 + 4 * g) = o;
        }
    } else {
        const size_t prow = (size_t)(chunk * 16 + bh) * 2048 + q0 + c;
        bf16_t* orow = Opart + prow * 64;
#pragma unroll
        for (int ct = 0; ct < 4; ++ct) {
            bf16x4 o;
#pragma unroll
            for (int i = 0; i < 4; ++i) o[i] = (bf16_t)acc[ct][i];
            *reinterpret_cast<bf16x4*>(orow + ct * 16 + 4 * g) = o;
        }
        if (g == 0) {
            float2 ml; ml.x = m_run; ml.y = l_tot;
            *reinterpret_cast<float2*>(ML + prow * 2) = ml;
        }
    }
}

// ---------------------------------------------------------------------------
// Kernel 2b: combine KV-split partials (bf16 O, f32 m/l) -> bf16 ctx. (R12)
// ---------------------------------------------------------------------------
template <int SPLIT>
__global__ __launch_bounds__(256) void combine_kernel(
    const bf16_t* __restrict__ Opart, const float* __restrict__ ML,
    bf16_t* __restrict__ CTX)
{
    const int gid = blockIdx.x * 256 + threadIdx.x;
    const int d4 = gid & 15, rowh = gid >> 4;
    const int bh = rowh >> 11, s = rowh & 2047;
    const int b = bh >> 3, h = bh & (H - 1);

    float m[SPLIT], l[SPLIT], M = -1e30f;
#pragma unroll
    for (int i = 0; i < SPLIT; ++i) {
        const float2 v = *reinterpret_cast<const float2*>(
            ML + ((size_t)(i * 16 + bh) * 2048 + s) * 2);
        m[i] = v.x; l[i] = v.y;
        M = fmaxf(M, m[i]);
    }
    f32x4 o = {0.f, 0.f, 0.f, 0.f};
    float wsum = 0.f;
#pragma unroll
    for (int i = 0; i < SPLIT; ++i) {
        const float w = fexp2(m[i] - M);
        wsum += w * l[i];
        const bf16x4 ov = *reinterpret_cast<const bf16x4*>(
            Opart + ((size_t)(i * 16 + bh) * 2048 + s) * 64 + d4 * 4);
#pragma unroll
        for (int j = 0; j < 4; ++j) o[j] += w * (float)ov[j];
    }
    const float inv = 1.0f / wsum;
    bf16x4 r;
#pragma unroll
    for (int i = 0; i < 4; ++i) r[i] = (bf16_t)(o[i] * inv);
    *reinterpret_cast<bf16x4*>(CTX + ((size_t)b * S + s) * 512 + h * 64 + d4 * 4) = r;
}

// ---------------------------------------------------------------------------
// Kernel 3: output projection via 64x64 gemm_tile (verified R14).
// grid 512 x 256 thr = 2 blocks/CU.
// ---------------------------------------------------------------------------
__global__ __launch_bounds__(256) void out_proj_kernel(
    const bf16_t* __restrict__ CTX,
    const bf16_t* __restrict__ WoT,
    const float* __restrict__ bo,
    float* __restrict__ out)
{
    __shared__ char lds[2][16384];

    const int mtile = blockIdx.x & 63;
    const int ntile = blockIdx.x >> 6;
    const int row0 = mtile * 64, n0 = ntile * 64;

    const int lane = threadIdx.x & 63;
    const int g = lane >> 4, c = lane & 15;
    const int wave = threadIdx.x >> 6, wm = wave >> 1, wn = wave & 1;

    const f32x4 zero = {0.f, 0.f, 0.f, 0.f};
    f32x4 acc[2][2] = {{zero, zero}, {zero, zero}};
    gemm_tile(CTX, WoT, row0, n0, &lds[0][0], acc);

#pragma unroll
    for (int mf = 0; mf < 2; ++mf)
#pragma unroll
        for (int nf = 0; nf < 2; ++nf) {
            const int n = n0 + wn * 32 + nf * 16 + c;
            const float bval = bo[n];
            const int rowb = row0 + wm * 32 + mf * 16 + 4 * g;
#pragma unroll
            for (int i = 0; i < 4; ++i)
                out[(size_t)(rowb + i) * 512 + n] = acc[mf][nf][i] + bval;
        }
}

// ---------------------------------------------------------------------------
extern "C" void kernel_launch(void* const* d_in, const int* in_sizes, int n_in,
                              void* d_out, int out_size, void* d_ws, size_t ws_size,
                              hipStream_t stream) {
    const float* query = (const float*)d_in[0];
    const float* key_  = (const float*)d_in[1];
    const float* value = (const float*)d_in[2];
    const float* Wq = (const float*)d_in[3];
    const float* bq = (const float*)d_in[4];
    const float* Wk = (const float*)d_in[5];
    const float* bk = (const float*)d_in[6];
    const float* Wv = (const float*)d_in[7];
    const float* bv = (const float*)d_in[8];
    const float* Wo = (const float*)d_in[9];
    const float* bo = (const float*)d_in[10];

    char* wsb = (char*)d_ws;
    bf16_t* Qw   = (bf16_t*)(wsb);                       // 4 MB
    bf16_t* Kw   = (bf16_t*)(wsb + (4u  << 20));         // 4 MB
    bf16_t* VTw  = (bf16_t*)(wsb + (8u  << 20));         // 4 MB
    bf16_t* CTXb = (bf16_t*)(wsb + (12u << 20));         // 4 MB
    bf16_t* Wtq  = (bf16_t*)(wsb + (16u << 20));         // 512 KB
    bf16_t* Wtk  = Wtq + 8 * 64 * 512;
    bf16_t* Wtv  = Wtk + 8 * 64 * 512;
    bf16_t* WoTw = (bf16_t*)(wsb + (18u << 20));         // 512 KB
    bf16_t* Xq   = (bf16_t*)(wsb + (20u << 20));         // 4 MB
    bf16_t* Xk   = (bf16_t*)(wsb + (24u << 20));         // 4 MB
    bf16_t* Xv   = (bf16_t*)(wsb + (28u << 20));         // 4 MB
    bf16_t* Opart = (bf16_t*)(wsb + (32u << 20));        // SPLIT x 4 MB (bf16)

    const int SPLIT = (ws_size >= (70ull << 20)) ? 4
                    : (ws_size >= (52ull << 20)) ? 2 : 1;

    prep_kernel<<<256 + 3072, 256, 0, stream>>>(Wq, Wk, Wv, Wo,
                                                query, key_, value,
                                                Wtq, Wtk, Wtv, WoTw,
                                                Xq, Xk, Xv);
    qkv_kernel<<<dim3(256, 3), 256, 0, stream>>>(Xq, Xk, Xv,
                                                 Wtq, Wtk, Wtv, bq, bk, bv,
                                                 Qw, Kw, VTw);

    if (SPLIT == 4) {
        float* MLp = (float*)(Opart + 4ull * 16 * 2048 * 64);
        attn_kernel<4><<<1024, 512, 0, stream>>>(Qw, Kw, VTw, CTXb, Opart, MLp);
        combine_kernel<4><<<2048, 256, 0, stream>>>(Opart, MLp, CTXb);
    } else if (SPLIT == 2) {
        float* MLp = (float*)(Opart + 2ull * 16 * 2048 * 64);
        attn_kernel<2><<<512, 512, 0, stream>>>(Qw, Kw, VTw, CTXb, Opart, MLp);
        combine_kernel<2><<<2048, 256, 0, stream>>>(Opart, MLp, CTXb);
    } else {
        attn_kernel<1><<<256, 512, 0, stream>>>(Qw, Kw, VTw, CTXb, nullptr, nullptr);
    }

    out_proj_kernel<<<512, 256, 0, stream>>>(CTXb, WoTw, bo, (float*)d_out);
}

// Round 17
// 64.188 us; speedup vs baseline: 1.1108x; 1.0017x over previous
//
#include <hip/hip_runtime.h>

#define B 2
#define S 2048
#define D 512
#define H 8
#define KD 64

typedef __bf16 bf16_t;
typedef __bf16 bf16x8 __attribute__((ext_vector_type(8)));
typedef __bf16 bf16x4 __attribute__((ext_vector_type(4)));
typedef float f32x4 __attribute__((ext_vector_type(4)));

#define QSCALE 0.1803368801111204f   /* 0.125 * log2(e): exp2-domain softmax */

__device__ __forceinline__ void async_copy16(const void* g, void* l) {
    __builtin_amdgcn_global_load_lds(
        (const __attribute__((address_space(1))) void*)g,
        (__attribute__((address_space(3))) void*)l, 16, 0, 0);
}

__device__ __forceinline__ float max3f(float a, float b, float c) {
    float d;
    asm("v_max3_f32 %0, %1, %2, %3" : "=v"(d) : "v"(a), "v"(b), "v"(c));
    return d;
}

// Raw 2^x (bounded inputs; big-negative -> 0 is wanted). Avoids libm guards.
#if __has_builtin(__builtin_amdgcn_exp2f)
__device__ __forceinline__ float fexp2(float x) { return __builtin_amdgcn_exp2f(x); }
#else
__device__ __forceinline__ float fexp2(float x) {
    float r;
    asm("v_exp_f32 %0, %1\n\ts_nop 1" : "=v"(r) : "v"(x));
    return r;
}
#endif

// ---------------------------------------------------------------------------
// Kernel 0: weight prep + X conversion, one launch. (verified R12)
// ---------------------------------------------------------------------------
__global__ __launch_bounds__(256) void prep_kernel(
    const float* __restrict__ Wq, const float* __restrict__ Wk,
    const float* __restrict__ Wv, const float* __restrict__ Wo,
    const float* __restrict__ qin, const float* __restrict__ kin, const float* __restrict__ vin,
    bf16_t* __restrict__ Wtq, bf16_t* __restrict__ Wtk,
    bf16_t* __restrict__ Wtv, bf16_t* __restrict__ WoT,
    bf16_t* __restrict__ xq, bf16_t* __restrict__ xk, bf16_t* __restrict__ xv)
{
    __shared__ bf16_t tl[64][72];
    const int blk = blockIdx.x, t = threadIdx.x;

    if (blk >= 256) {   // ---- xcvt part ----
        const int idx = blk - 256;
        const int mat = idx >> 10, cidx = idx & 1023;
        const float* src = (mat == 0) ? qin : (mat == 1) ? kin : vin;
        bf16_t* dst = (mat == 0) ? xq : (mat == 1) ? xk : xv;
        const size_t i8 = ((size_t)cidx * 256 + t) * 8;
        const float4 f0 = *reinterpret_cast<const float4*>(src + i8);
        const float4 f1 = *reinterpret_cast<const float4*>(src + i8 + 4);
        bf16x8 o;
        o[0] = (bf16_t)f0.x; o[1] = (bf16_t)f0.y; o[2] = (bf16_t)f0.z; o[3] = (bf16_t)f0.w;
        o[4] = (bf16_t)f1.x; o[5] = (bf16_t)f1.y; o[6] = (bf16_t)f1.z; o[7] = (bf16_t)f1.w;
        *reinterpret_cast<bf16x8*>(dst + i8) = o;
        return;
    }

    const float* src; bf16_t* dstbase;
    int ld, r0, c0;
    if (blk < 192) {
        const int mat = blk >> 6, h = (blk & 63) >> 3, dt = blk & 7;
        const float* W = (mat == 0) ? Wq : (mat == 1) ? Wk : Wv;
        bf16_t* Wt = (mat == 0) ? Wtq : (mat == 1) ? Wtk : Wtv;
        src = W + (size_t)h * D * KD; dstbase = Wt + (size_t)h * KD * D;
        ld = KD; r0 = dt * 64; c0 = 0;
    } else {
        const int kt = (blk - 192) >> 3, nt = (blk - 192) & 7;
        src = Wo; dstbase = WoT;
        ld = D; r0 = kt * 64; c0 = nt * 64;
    }

    {
        const int r = t >> 2, cq = (t & 3) * 16;
        const float* sp = src + (size_t)(r0 + r) * ld + c0 + cq;
#pragma unroll
        for (int q = 0; q < 4; ++q) {
            const float4 f = *reinterpret_cast<const float4*>(sp + q * 4);
            tl[r][cq + q * 4 + 0] = (bf16_t)f.x; tl[r][cq + q * 4 + 1] = (bf16_t)f.y;
            tl[r][cq + q * 4 + 2] = (bf16_t)f.z; tl[r][cq + q * 4 + 3] = (bf16_t)f.w;
        }
    }
    __syncthreads();
    {
        const int cc = t >> 2, rq = (t & 3) * 16;
        bf16x8 o0, o1;
#pragma unroll
        for (int j = 0; j < 8; ++j) { o0[j] = tl[rq + j][cc]; o1[j] = tl[rq + 8 + j][cc]; }
        bf16_t* dp = dstbase + (size_t)(c0 + cc) * 512 + r0 + rq;
        *reinterpret_cast<bf16x8*>(dp) = o0;
        *reinterpret_cast<bf16x8*>(dp + 8) = o1;
    }
}

// ---------------------------------------------------------------------------
// Shared 64x64 GEMM mainloop (verified R9) — used by out_proj (512 blocks =
// 2 blocks/CU; the 128-tile variant at 256 blocks = 1 block/CU regressed).
// ---------------------------------------------------------------------------
__device__ __forceinline__ void gemm_tile(
    const bf16_t* __restrict__ A, const bf16_t* __restrict__ Bt,
    int row0, int n0, char* lds, f32x4 (&acc)[2][2])
{
    const int tid = threadIdx.x, wave = tid >> 6, lane = tid & 63;
    const int g = lane >> 4, c = lane & 15;

    const int srow8 = lane >> 3, sslot = lane & 7;
    const bf16_t* asrc[2]; const bf16_t* bsrc[2];
#pragma unroll
    for (int j = 0; j < 2; ++j) {
        const int r = wave * 16 + j * 8 + srow8;
        const int ys = (r & 7) ^ (((r >> 3) & 1) << 2);
        asrc[j] = A + (size_t)(row0 + r) * 512 + ((sslot ^ ys) << 3);
        bsrc[j] = Bt + (size_t)(n0 + r) * 512 + ((sslot ^ ys) << 3);
    }
    const int adst = wave * 2048;
    const int bdst = 8192 + wave * 2048;

    const int ysr = (c & 7) ^ (((c >> 3) & 1) << 2);
    const int wm = wave >> 1, wn = wave & 1;
    int ard[2], brd[2];
#pragma unroll
    for (int f = 0; f < 2; ++f) {
        ard[f] = (wm * 32 + f * 16 + c) * 128;
        brd[f] = 8192 + (wn * 32 + f * 16 + c) * 128;
    }

#define GSTAGE(bufi, kt)                                                       \
    do { char* bp = lds + (bufi) * 16384;                                      \
        _Pragma("unroll") for (int j = 0; j < 2; ++j) {                        \
            async_copy16(asrc[j] + (kt) * 64, bp + adst + j * 1024);           \
            async_copy16(bsrc[j] + (kt) * 64, bp + bdst + j * 1024);           \
        }                                                                      \
    } while (0)

    int buf = 0;
    GSTAGE(0, 0);
    __syncthreads();
#pragma unroll 1
    for (int kt = 0; kt < 8; ++kt) {
        if (kt < 7) GSTAGE(buf ^ 1, kt + 1);
        const char* bp = lds + buf * 16384;
        __builtin_amdgcn_s_setprio(1);
#pragma unroll
        for (int ksub = 0; ksub < 2; ++ksub) {
            const int so = (((ksub << 2) | g) ^ ysr) << 4;
            bf16x8 bfr[2];
#pragma unroll
            for (int nf = 0; nf < 2; ++nf)
                bfr[nf] = *reinterpret_cast<const bf16x8*>(bp + brd[nf] + so);
#pragma unroll
            for (int mf = 0; mf < 2; ++mf) {
                const bf16x8 afr = *reinterpret_cast<const bf16x8*>(bp + ard[mf] + so);
                acc[mf][0] = __builtin_amdgcn_mfma_f32_16x16x32_bf16(afr, bfr[0], acc[mf][0], 0, 0, 0);
                acc[mf][1] = __builtin_amdgcn_mfma_f32_16x16x32_bf16(afr, bfr[1], acc[mf][1], 0, 0, 0);
            }
        }
        __builtin_amdgcn_s_setprio(0);
        __syncthreads();
        buf ^= 1;
    }
#undef GSTAGE
}

// ---------------------------------------------------------------------------
// Kernel 1: fused QKV projection, 128x64 tile (verified R14).
// grid (256, 3) x 256 thr = 768 blocks = 3 blocks/CU at 48 KB LDS.
// ---------------------------------------------------------------------------
__global__ __launch_bounds__(256) void qkv_kernel(
    const bf16_t* __restrict__ xq, const bf16_t* __restrict__ xk, const bf16_t* __restrict__ xv,
    const bf16_t* __restrict__ Wtq, const bf16_t* __restrict__ Wtk, const bf16_t* __restrict__ Wtv,
    const float* __restrict__ bq, const float* __restrict__ bk, const float* __restrict__ bv,
    bf16_t* __restrict__ Qo, bf16_t* __restrict__ Ko, bf16_t* __restrict__ VTo)
{
    __shared__ char lds[2][24576];   // A [128][128B] | B [64][128B] per buf

    const int mat = blockIdx.y;
    const bf16_t* A    = (mat == 0) ? xq  : (mat == 1) ? xk  : xv;
    const bf16_t* Bt   = (mat == 0) ? Wtq : (mat == 1) ? Wtk : Wtv;
    const float* bias  = (mat == 0) ? bq  : (mat == 1) ? bk  : bv;
    const float scale  = (mat == 0) ? QSCALE : 1.0f;

    const int mtile = blockIdx.x & 31;      // low bits -> XCD (A-panel sharers co-XCD)
    const int ntile = blockIdx.x >> 5;      // 0..7
    const int row0 = mtile * 128, n0 = ntile * 64;

    const int tid = threadIdx.x, wave = tid >> 6, lane = tid & 63;
    const int g = lane >> 4, c = lane & 15;
    const int srow8 = lane >> 3, sslot = lane & 7;

    const bf16_t* asrc[4]; const bf16_t* bsrc[2];
#pragma unroll
    for (int j = 0; j < 4; ++j) {
        const int r = wave * 32 + j * 8 + srow8;
        const int ys = srow8 ^ ((j & 1) << 2);
        asrc[j] = A + (size_t)(row0 + r) * 512 + ((sslot ^ ys) << 3);
    }
#pragma unroll
    for (int j = 0; j < 2; ++j) {
        const int r = wave * 16 + j * 8 + srow8;
        const int ys = srow8 ^ ((j & 1) << 2);
        bsrc[j] = Bt + (size_t)(n0 + r) * 512 + ((sslot ^ ys) << 3);
    }
    const int adst = wave * 4096;
    const int bdst = 16384 + wave * 2048;

    const int ysr = (c & 7) ^ (((c >> 3) & 1) << 2);
    const int wm = wave >> 1, wn = wave & 1;
    int ard[4], brd[2];
#pragma unroll
    for (int f = 0; f < 4; ++f) ard[f] = (wm * 64 + f * 16 + c) * 128;
#pragma unroll
    for (int f = 0; f < 2; ++f) brd[f] = 16384 + (wn * 32 + f * 16 + c) * 128;

    const f32x4 zero = {0.f, 0.f, 0.f, 0.f};
    f32x4 acc[4][2] = {{zero, zero}, {zero, zero}, {zero, zero}, {zero, zero}};

#define QSTAGE(bufi, kt)                                                       \
    do { char* bp = lds[bufi];                                                 \
        _Pragma("unroll") for (int j = 0; j < 4; ++j)                          \
            async_copy16(asrc[j] + (kt) * 64, bp + adst + j * 1024);           \
        _Pragma("unroll") for (int j = 0; j < 2; ++j)                          \
            async_copy16(bsrc[j] + (kt) * 64, bp + bdst + j * 1024);           \
    } while (0)

    int buf = 0;
    QSTAGE(0, 0);
    __syncthreads();
#pragma unroll 1
    for (int kt = 0; kt < 8; ++kt) {
        if (kt < 7) QSTAGE(buf ^ 1, kt + 1);
        const char* bp = lds[buf];
        __builtin_amdgcn_s_setprio(1);
#pragma unroll
        for (int ksub = 0; ksub < 2; ++ksub) {
            const int so = (((ksub << 2) | g) ^ ysr) << 4;
            const bf16x8 bfr0 = *reinterpret_cast<const bf16x8*>(bp + brd[0] + so);
            const bf16x8 bfr1 = *reinterpret_cast<const bf16x8*>(bp + brd[1] + so);
#pragma unroll
            for (int mf = 0; mf < 4; ++mf) {
                const bf16x8 afr = *reinterpret_cast<const bf16x8*>(bp + ard[mf] + so);
                acc[mf][0] = __builtin_amdgcn_mfma_f32_16x16x32_bf16(afr, bfr0, acc[mf][0], 0, 0, 0);
                acc[mf][1] = __builtin_amdgcn_mfma_f32_16x16x32_bf16(afr, bfr1, acc[mf][1], 0, 0, 0);
            }
        }
        __builtin_amdgcn_s_setprio(0);
        __syncthreads();
        buf ^= 1;
    }
#undef QSTAGE

#pragma unroll
    for (int mf = 0; mf < 4; ++mf)
#pragma unroll
        for (int nf = 0; nf < 2; ++nf) {
            const int n = n0 + wn * 32 + nf * 16 + c;
            const int h = n >> 6, col = n & 63;
            const float bval = bias[n];
            const int rowb = row0 + wm * 64 + mf * 16 + 4 * g;
            const int b = rowb >> 11, s0 = rowb & 2047;
            const int bh = b * H + h;
            if (mat < 2) {
                bf16_t* outp = (mat == 0) ? Qo : Ko;
#pragma unroll
                for (int i = 0; i < 4; ++i)
                    outp[((size_t)bh * S + s0 + i) * KD + col] =
                        (bf16_t)((acc[mf][nf][i] + bval) * scale);
            } else {
                bf16x4 o;
#pragma unroll
                for (int i = 0; i < 4; ++i) o[i] = (bf16_t)(acc[mf][nf][i] + bval);
                *reinterpret_cast<bf16x4*>(VTo + ((size_t)bh * KD + col) * S + s0) = o;
            }
        }
}

// ---------------------------------------------------------------------------
// Kernel 2: flash attention, KV-split (verified R12).
// ---------------------------------------------------------------------------
template <int SPLIT>
__global__ __launch_bounds__(512) void attn_kernel(
    const bf16_t* __restrict__ Q, const bf16_t* __restrict__ Km,
    const bf16_t* __restrict__ VT,
    bf16_t* __restrict__ CTX, bf16_t* __restrict__ Opart, float* __restrict__ ML)
{
    __shared__ char kv_lds[2][16384];

    const int hw = blockIdx.x;
    const int xcd = hw & 7;
    const int idx = hw >> 3;
    const int bh = xcd * 2 + (idx >= 16 * SPLIT ? 1 : 0);
    const int r2 = idx & (16 * SPLIT - 1);
    const int chunk = r2 >> 4;
    const int stile = r2 & 15;
    const int b = bh >> 3, h = bh & (H - 1);

    const int tid = threadIdx.x, wave = tid >> 6, lane = tid & 63;
    const int g = lane >> 4, c = lane & 15;
    const int q0 = stile * 128 + wave * 16;
    const int kvbeg = chunk * (S / SPLIT);
    const int NT = (S / SPLIT) / 64;

    const bf16_t* kg = Km + (size_t)bh * S * KD;
    const bf16_t* vg = VT + (size_t)bh * KD * S;

    const bf16_t* qp = Q + ((size_t)bh * S + q0 + c) * KD;
    const bf16x8 qlo = *reinterpret_cast<const bf16x8*>(qp + g * 8);
    const bf16x8 qhi = *reinterpret_cast<const bf16x8*>(qp + 32 + g * 8);

    bf16x8 ones;
#pragma unroll
    for (int i = 0; i < 8; ++i) ones[i] = (bf16_t)1.0f;

    int koff[4][2], voff[4][2];
#pragma unroll
    for (int tt = 0; tt < 4; ++tt) {
        const int row = 8 * (c >> 2) + (c & 3) + 4 * (tt & 1) + 32 * (tt >> 1);
        const int ys = (row & 7) ^ (((row >> 3) & 1) << 2);
        koff[tt][0] = row * 128 + ((g * 16) ^ (ys << 4));
        koff[tt][1] = row * 128 + ((64 + g * 16) ^ (ys << 4));
    }
#pragma unroll
    for (int ct = 0; ct < 4; ++ct) {
        const int row = ct * 16 + c;
        const int ys = (row & 7) ^ (((row >> 3) & 1) << 2);
        voff[ct][0] = 8192 + row * 128 + ((g * 16) ^ (ys << 4));
        voff[ct][1] = 8192 + row * 128 + ((64 + g * 16) ^ (ys << 4));
    }

    const int srow = lane >> 3, sslot = lane & 7;
    const int kwv = wave & 3;
    const int krow0a = kwv * 16, krow0b = kwv * 16 + 8;
    const int rowa = krow0a + srow, rowb = krow0b + srow;
    const int ysa = (rowa & 7) ^ (((rowa >> 3) & 1) << 2);
    const int ysb = (rowb & 7) ^ (((rowb >> 3) & 1) << 2);
    const int ssa = sslot ^ ysa, ssb = sslot ^ ysb;

    const f32x4 zero = {0.f, 0.f, 0.f, 0.f};
    f32x4 acc[4] = {zero, zero, zero, zero};
    f32x4 accl = zero;
    float m_run = -1e30f;

#define STAGE(bufidx, kv0)                                                        \
    do {                                                                          \
        char* bp = kv_lds[0] + (bufidx) * 16384;                                  \
        if (wave < 4) {                                                           \
            async_copy16(kg + (size_t)((kv0) + rowa) * KD + ssa * 8, bp + krow0a * 128); \
            async_copy16(kg + (size_t)((kv0) + rowb) * KD + ssb * 8, bp + krow0b * 128); \
        } else {                                                                  \
            async_copy16(vg + (size_t)rowa * S + (kv0) + ssa * 8, bp + 8192 + krow0a * 128); \
            async_copy16(vg + (size_t)rowb * S + (kv0) + ssb * 8, bp + 8192 + krow0b * 128); \
        }                                                                         \
    } while (0)

    STAGE(0, kvbeg);
    __syncthreads();

    int buf = 0;
    for (int t = 0; t < NT; ++t) {
        if (t < NT - 1) STAGE(buf ^ 1, kvbeg + (t + 1) * 64);
        const char* kb = kv_lds[0] + buf * 16384;

        f32x4 sc[4];
        __builtin_amdgcn_s_setprio(1);
#pragma unroll
        for (int tt = 0; tt < 4; ++tt) {
            const bf16x8 k0f = *reinterpret_cast<const bf16x8*>(kb + koff[tt][0]);
            const bf16x8 k1f = *reinterpret_cast<const bf16x8*>(kb + koff[tt][1]);
            f32x4 z = zero;
            z = __builtin_amdgcn_mfma_f32_16x16x32_bf16(k0f, qlo, z, 0, 0, 0);
            sc[tt] = __builtin_amdgcn_mfma_f32_16x16x32_bf16(k1f, qhi, z, 0, 0, 0);
        }
        __builtin_amdgcn_s_setprio(0);

        const float m0 = max3f(sc[0][0], sc[0][1], sc[0][2]);
        const float m1 = max3f(sc[0][3], sc[1][0], sc[1][1]);
        const float m2 = max3f(sc[1][2], sc[1][3], sc[2][0]);
        const float m3 = max3f(sc[2][1], sc[2][2], sc[2][3]);
        const float m4 = max3f(sc[3][0], sc[3][1], sc[3][2]);
        float pm = fmaxf(max3f(max3f(m0, m1, m2), m3, m4), sc[3][3]);
        if (!__all(pm <= m_run + 8.0f)) {
            pm = fmaxf(pm, __shfl_xor(pm, 16));
            pm = fmaxf(pm, __shfl_xor(pm, 32));
            const float mn = fmaxf(m_run, pm);
            const float fs = fexp2(m_run - mn);
            m_run = mn;
            accl = accl * fs;
#pragma unroll
            for (int ct = 0; ct < 4; ++ct) acc[ct] = acc[ct] * fs;
        }

        bf16x8 f0, f1;
#pragma unroll
        for (int i = 0; i < 4; ++i) {
            f0[i]     = (bf16_t)fexp2(sc[0][i] - m_run);
            f0[4 + i] = (bf16_t)fexp2(sc[1][i] - m_run);
            f1[i]     = (bf16_t)fexp2(sc[2][i] - m_run);
            f1[4 + i] = (bf16_t)fexp2(sc[3][i] - m_run);
        }

        __builtin_amdgcn_s_setprio(1);
        accl = __builtin_amdgcn_mfma_f32_16x16x32_bf16(ones, f0, accl, 0, 0, 0);
        accl = __builtin_amdgcn_mfma_f32_16x16x32_bf16(ones, f1, accl, 0, 0, 0);
#pragma unroll
        for (int ct = 0; ct < 4; ++ct) {
            const bf16x8 v0f = *reinterpret_cast<const bf16x8*>(kb + voff[ct][0]);
            const bf16x8 v1f = *reinterpret_cast<const bf16x8*>(kb + voff[ct][1]);
            acc[ct] = __builtin_amdgcn_mfma_f32_16x16x32_bf16(v0f, f0, acc[ct], 0, 0, 0);
            acc[ct] = __builtin_amdgcn_mfma_f32_16x16x32_bf16(v1f, f1, acc[ct], 0, 0, 0);
        }
        __builtin_amdgcn_s_setprio(0);

        __syncthreads();
        buf ^= 1;
    }
#undef STAGE

    const float l_tot = accl[0];

    if constexpr (SPLIT == 1) {
        const float inv = 1.0f / l_tot;
        bf16_t* crow = CTX + ((size_t)b * S + q0 + c) * 512 + h * 64;
#pragma unroll
        for (int ct = 0; ct < 4; ++ct) {
            bf16x4 o;
#pragma unroll
            for (int i = 0; i < 4; ++i) o[i] = (bf16_t)(acc[ct][i] * inv);
            *reinterpret_cast<bf16x4*>(crow + ct * 16 + 4 * g) = o;
        }
    } else {
        const size_t prow = (size_t)(chunk * 16 + bh) * 2048 + q0 + c;
        bf16_t* orow = Opart + prow * 64;
#pragma unroll
        for (int ct = 0; ct < 4; ++ct) {
            bf16x4 o;
#pragma unroll
            for (int i = 0; i < 4; ++i) o[i] = (bf16_t)acc[ct][i];
            *reinterpret_cast<bf16x4*>(orow + ct * 16 + 4 * g) = o;
        }
        if (g == 0) {
            float2 ml; ml.x = m_run; ml.y = l_tot;
            *reinterpret_cast<float2*>(ML + prow * 2) = ml;
        }
    }
}

// ---------------------------------------------------------------------------
// Kernel 2b: combine KV-split partials (bf16 O, f32 m/l) -> bf16 ctx. (R12)
// ---------------------------------------------------------------------------
template <int SPLIT>
__global__ __launch_bounds__(256) void combine_kernel(
    const bf16_t* __restrict__ Opart, const float* __restrict__ ML,
    bf16_t* __restrict__ CTX)
{
    const int gid = blockIdx.x * 256 + threadIdx.x;
    const int d4 = gid & 15, rowh = gid >> 4;
    const int bh = rowh >> 11, s = rowh & 2047;
    const int b = bh >> 3, h = bh & (H - 1);

    float m[SPLIT], l[SPLIT], M = -1e30f;
#pragma unroll
    for (int i = 0; i < SPLIT; ++i) {
        const float2 v = *reinterpret_cast<const float2*>(
            ML + ((size_t)(i * 16 + bh) * 2048 + s) * 2);
        m[i] = v.x; l[i] = v.y;
        M = fmaxf(M, m[i]);
    }
    f32x4 o = {0.f, 0.f, 0.f, 0.f};
    float wsum = 0.f;
#pragma unroll
    for (int i = 0; i < SPLIT; ++i) {
        const float w = fexp2(m[i] - M);
        wsum += w * l[i];
        const bf16x4 ov = *reinterpret_cast<const bf16x4*>(
            Opart + ((size_t)(i * 16 + bh) * 2048 + s) * 64 + d4 * 4);
#pragma unroll
        for (int j = 0; j < 4; ++j) o[j] += w * (float)ov[j];
    }
    const float inv = 1.0f / wsum;
    bf16x4 r;
#pragma unroll
    for (int i = 0; i < 4; ++i) r[i] = (bf16_t)(o[i] * inv);
    *reinterpret_cast<bf16x4*>(CTX + ((size_t)b * S + s) * 512 + h * 64 + d4 * 4) = r;
}

// ---------------------------------------------------------------------------
// Kernel 3: output projection via 64x64 gemm_tile (verified R14).
// grid 512 x 256 thr = 2 blocks/CU.
// ---------------------------------------------------------------------------
__global__ __launch_bounds__(256) void out_proj_kernel(
    const bf16_t* __restrict__ CTX,
    const bf16_t* __restrict__ WoT,
    const float* __restrict__ bo,
    float* __restrict__ out)
{
    __shared__ char lds[2][16384];

    const int mtile = blockIdx.x & 63;
    const int ntile = blockIdx.x >> 6;
    const int row0 = mtile * 64, n0 = ntile * 64;

    const int lane = threadIdx.x & 63;
    const int g = lane >> 4, c = lane & 15;
    const int wave = threadIdx.x >> 6, wm = wave >> 1, wn = wave & 1;

    const f32x4 zero = {0.f, 0.f, 0.f, 0.f};
    f32x4 acc[2][2] = {{zero, zero}, {zero, zero}};
    gemm_tile(CTX, WoT, row0, n0, &lds[0][0], acc);

#pragma unroll
    for (int mf = 0; mf < 2; ++mf)
#pragma unroll
        for (int nf = 0; nf < 2; ++nf) {
            const int n = n0 + wn * 32 + nf * 16 + c;
            const float bval = bo[n];
            const int rowb = row0 + wm * 32 + mf * 16 + 4 * g;
#pragma unroll
            for (int i = 0; i < 4; ++i)
                out[(size_t)(rowb + i) * 512 + n] = acc[mf][nf][i] + bval;
        }
}

// ---------------------------------------------------------------------------
extern "C" void kernel_launch(void* const* d_in, const int* in_sizes, int n_in,
                              void* d_out, int out_size, void* d_ws, size_t ws_size,
                              hipStream_t stream) {
    const float* query = (const float*)d_in[0];
    const float* key_  = (const float*)d_in[1];
    const float* value = (const float*)d_in[2];
    const float* Wq = (const float*)d_in[3];
    const float* bq = (const float*)d_in[4];
    const float* Wk = (const float*)d_in[5];
    const float* bk = (const float*)d_in[6];
    const float* Wv = (const float*)d_in[7];
    const float* bv = (const float*)d_in[8];
    const float* Wo = (const float*)d_in[9];
    const float* bo = (const float*)d_in[10];

    char* wsb = (char*)d_ws;
    bf16_t* Qw   = (bf16_t*)(wsb);                       // 4 MB
    bf16_t* Kw   = (bf16_t*)(wsb + (4u  << 20));         // 4 MB
    bf16_t* VTw  = (bf16_t*)(wsb + (8u  << 20));         // 4 MB
    bf16_t* CTXb = (bf16_t*)(wsb + (12u << 20));         // 4 MB
    bf16_t* Wtq  = (bf16_t*)(wsb + (16u << 20));         // 512 KB
    bf16_t* Wtk  = Wtq + 8 * 64 * 512;
    bf16_t* Wtv  = Wtk + 8 * 64 * 512;
    bf16_t* WoTw = (bf16_t*)(wsb + (18u << 20));         // 512 KB
    bf16_t* Xq   = (bf16_t*)(wsb + (20u << 20));         // 4 MB
    bf16_t* Xk   = (bf16_t*)(wsb + (24u << 20));         // 4 MB
    bf16_t* Xv   = (bf16_t*)(wsb + (28u << 20));         // 4 MB
    bf16_t* Opart = (bf16_t*)(wsb + (32u << 20));        // SPLIT x 4 MB (bf16)

    // ws_size has been 268 MB in all observed runs -> SPLIT=4 path; SPLIT=1
    // kept as the safety fallback only (SPLIT=2 instantiation removed).
    const int SPLIT = (ws_size >= (70ull << 20)) ? 4 : 1;

    prep_kernel<<<256 + 3072, 256, 0, stream>>>(Wq, Wk, Wv, Wo,
                                                query, key_, value,
                                                Wtq, Wtk, Wtv, WoTw,
                                                Xq, Xk, Xv);
    qkv_kernel<<<dim3(256, 3), 256, 0, stream>>>(Xq, Xk, Xv,
                                                 Wtq, Wtk, Wtv, bq, bk, bv,
                                                 Qw, Kw, VTw);

    if (SPLIT == 4) {
        float* MLp = (float*)(Opart + 4ull * 16 * 2048 * 64);
        attn_kernel<4><<<1024, 512, 0, stream>>>(Qw, Kw, VTw, CTXb, Opart, MLp);
        combine_kernel<4><<<2048, 256, 0, stream>>>(Opart, MLp, CTXb);
    } else {
        attn_kernel<1><<<256, 512, 0, stream>>>(Qw, Kw, VTw, CTXb, nullptr, nullptr);
    }

    out_proj_kernel<<<512, 256, 0, stream>>>(CTXb, WoTw, bo, (float*)d_out);
}